// Round 2
// baseline (61.941 us; speedup 1.0000x reference)
//
#include <hip/hip_runtime.h>
#include <math.h>

#define B_    32
#define PPB   256
#define N_    (B_*PPB)     // 8192 proposals / padded slots
#define M_    128
#define LANG_ 256
#define H_    128
#define EPS_  1e-5f

#define MC    16           // columns per MLP block
#define MB    (N_/MC)      // 512 blocks
#define MT    256          // threads per MLP block

// ---------------------------------------------------------------------------
// Kernel A: per-proposal batch id, within-chunk stable rank, chunk histograms,
// plus fused language projection lp[b][o] = W_fuse[o,128:384] . lang_emb[b].
// One block per 256-proposal chunk (chunk id == batch id for the lang part).
// ---------------------------------------------------------------------------
__global__ __launch_bounds__(256) void k_map_a(
    const int* __restrict__ pidx, const int* __restrict__ poff,
    const int* __restrict__ boff, int* __restrict__ bid_g,
    int* __restrict__ wrank_g, int* __restrict__ hist_g,
    int* __restrict__ src_of_dest,
    const float* __restrict__ Wf, const float* __restrict__ lang,
    float* __restrict__ lp)
{
  __shared__ int sb[33];
  __shared__ int sbid[256];
  __shared__ int shist[32];
  const int tid = threadIdx.x;
  const int i = blockIdx.x * 256 + tid;
  if (tid < 33) sb[tid] = boff[tid];
  if (tid < 32) shist[tid] = 0;
  __syncthreads();
  const int off = poff[i];
  const int fp  = pidx[2 * off + 1];
  int cnt = 0;
  #pragma unroll
  for (int j = 0; j < 33; ++j) cnt += (sb[j] <= fp) ? 1 : 0;
  int bd = cnt - 1;
  bd = bd < 0 ? 0 : (bd > 31 ? 31 : bd);
  sbid[tid] = bd;
  bid_g[i] = bd;
  src_of_dest[i] = -1;          // init inverse map (N_ == B_*PPB)
  atomicAdd(&shist[bd], 1);
  __syncthreads();
  // stable rank within chunk (brute force over <=255 LDS words)
  int r = 0;
  for (int j = 0; j < tid; ++j) r += (sbid[j] == bd) ? 1 : 0;
  wrank_g[i] = r;
  if (tid < 32) hist_g[blockIdx.x * 32 + tid] = shist[tid];

  // fused lang projection (batch = blockIdx.x)
  if (tid < 128) {
    const int o = tid;
    float acc = 0.f;
    for (int l = 0; l < LANG_; l += 4) {
      const float4 w = *reinterpret_cast<const float4*>(Wf + o * 384 + 128 + l);
      const float4 e = *reinterpret_cast<const float4*>(lang + blockIdx.x * LANG_ + l);
      acc += w.x * e.x + w.y * e.y + w.z * e.z + w.w * e.w;
    }
    lp[blockIdx.x * H_ + o] = acc;
  }
}

// ---------------------------------------------------------------------------
// Kernel B: cross-chunk exclusive scan per bin, scatter inverse map, fold BN.
// Single block, 1024 threads.
// ---------------------------------------------------------------------------
__global__ __launch_bounds__(1024) void k_map_b(
    const int* __restrict__ bid_g, const int* __restrict__ wrank_g,
    const int* __restrict__ hist_g, int* __restrict__ src_of_dest,
    const float* __restrict__ g1, const float* __restrict__ be1,
    const float* __restrict__ rm1, const float* __restrict__ rv1,
    const float* __restrict__ g2, const float* __restrict__ be2,
    const float* __restrict__ rm2, const float* __restrict__ rv2,
    float* __restrict__ s1, float* __restrict__ t1,
    float* __restrict__ s2, float* __restrict__ t2)
{
  __shared__ int cb[32][32];   // cb[chunk][bin] = exclusive prefix of hist over chunks
  const int tid = threadIdx.x;
  if (tid < 32) {
    int run = 0;
    for (int c = 0; c < 32; ++c) { cb[c][tid] = run; run += hist_g[c * 32 + tid]; }
  } else if (tid >= 512 && tid < 640) {
    const int o = tid - 512;
    const float s = g1[o] / sqrtf(rv1[o] + EPS_);
    s1[o] = s; t1[o] = be1[o] - rm1[o] * s;
  } else if (tid >= 640 && tid < 768) {
    const int o = tid - 640;
    const float s = g2[o] / sqrtf(rv2[o] + EPS_);
    s2[o] = s; t2[o] = be2[o] - rm2[o] * s;
  }
  __syncthreads();
  #pragma unroll
  for (int k = 0; k < 8; ++k) {
    const int i = tid * 8 + k;
    const int bd = bid_g[i];
    const int rank = cb[i >> 8][bd] + wrank_g[i];
    if (rank < PPB) src_of_dest[bd * PPB + rank] = i;   // OOB updates dropped
  }
}

// ---------------------------------------------------------------------------
// Kernel D: fused MLP. 512 blocks x 256 threads, 16 columns per block.
// Weights staged through a 32KB LDS chunk (64 output rows, padded stride 132),
// next chunk register-prefetched during compute. Activations ping through
// one LDS buffer with in-register layer outputs.
// ---------------------------------------------------------------------------
__global__ __launch_bounds__(MT) void k_mlp(
    const float* __restrict__ feats,
    const float* __restrict__ Wf, const float* __restrict__ bf,
    const float* __restrict__ W1, const float* __restrict__ b1,
    const float* __restrict__ W2, const float* __restrict__ b2,
    const float* __restrict__ W3, const float* __restrict__ b3,
    const int* __restrict__ src_of_dest, const float* __restrict__ lp,
    const float* __restrict__ s1, const float* __restrict__ t1,
    const float* __restrict__ s2, const float* __restrict__ t2,
    float* __restrict__ out)
{
  __shared__ float wlds[64 * 132];      // one 64-output weight chunk, padded rows
  __shared__ float act[MC][132];        // activations [col][chan], padded

  const int tid = threadIdx.x;
  const int q0 = blockIdx.x * MC;
  const int b  = q0 >> 8;               // MC divides PPB -> whole block same batch
  const int col = tid & 15;
  const int og  = tid >> 4;             // 16 output groups of 4

  // chunk sources: {ptr, row stride}; L0 = Wf[:, :128], chunks = 64-row halves
  const float* csrc[6] = { Wf, Wf + 64 * 384, W1, W1 + 64 * H_, W2, W2 + 64 * H_ };
  const int cstr[6] = { 384, 384, H_, H_, H_, H_ };

  float4 pf[8];
  // issue prefetch of chunk 0
  {
    const float* p = csrc[0]; const int st = cstr[0];
    #pragma unroll
    for (int j = 0; j < 8; ++j) {
      const int f = j * MT + tid, r = f >> 5, c4 = f & 31;
      pf[j] = *reinterpret_cast<const float4*>(p + r * st + c4 * 4);
    }
  }
  // gather feats into act
  {
    const int r = tid >> 4;                 // 16 rows
    const int srow = src_of_dest[q0 + r];
    const int c4a = tid & 15, c4b = (tid & 15) + 16;
    float4 va = make_float4(0.f, 0.f, 0.f, 0.f), vb = va;
    if (srow >= 0) {
      va = *reinterpret_cast<const float4*>(feats + (size_t)srow * M_ + c4a * 4);
      vb = *reinterpret_cast<const float4*>(feats + (size_t)srow * M_ + c4b * 4);
    }
    *reinterpret_cast<float4*>(&act[r][c4a * 4]) = va;
    *reinterpret_cast<float4*>(&act[r][c4b * 4]) = vb;
  }
  // write chunk 0 to LDS, issue prefetch of chunk 1
  #pragma unroll
  for (int j = 0; j < 8; ++j) {
    const int f = j * MT + tid, r = f >> 5, c4 = f & 31;
    *reinterpret_cast<float4*>(&wlds[r * 132 + c4 * 4]) = pf[j];
  }
  {
    const float* p = csrc[1]; const int st = cstr[1];
    #pragma unroll
    for (int j = 0; j < 8; ++j) {
      const int f = j * MT + tid, r = f >> 5, c4 = f & 31;
      pf[j] = *reinterpret_cast<const float4*>(p + r * st + c4 * 4);
    }
  }
  __syncthreads();

  float resA[4], resB[4];

  #pragma unroll
  for (int ph = 0; ph < 6; ++ph) {
    const int layer = ph >> 1, half = ph & 1;
    float acc[4] = {0.f, 0.f, 0.f, 0.f};
    #pragma unroll 4
    for (int c = 0; c < H_; c += 4) {
      const float4 xa = *reinterpret_cast<const float4*>(&act[col][c]);
      #pragma unroll
      for (int k = 0; k < 4; ++k) {
        const float4 w = *reinterpret_cast<const float4*>(&wlds[(og * 4 + k) * 132 + c]);
        acc[k] += w.x * xa.x + w.y * xa.y + w.z * xa.z + w.w * xa.w;
      }
    }
    // nonlinearity / BN fold
    #pragma unroll
    for (int k = 0; k < 4; ++k) {
      const int o = half * 64 + og * 4 + k;
      float v;
      if (layer == 0)      v = fmaxf(acc[k] + lp[b * H_ + o] + bf[o], 0.f);
      else if (layer == 1) v = fmaxf(acc[k] + b1[o], 0.f) * s1[o] + t1[o];
      else                 v = fmaxf(acc[k] + b2[o], 0.f) * s2[o] + t2[o];
      if (half == 0) resA[k] = v; else resB[k] = v;
    }
    __syncthreads();   // all reads of wlds (and act, if half==1) complete

    if (ph < 5) {
      // commit prefetched chunk ph+1 to LDS
      #pragma unroll
      for (int j = 0; j < 8; ++j) {
        const int f = j * MT + tid, r = f >> 5, c4 = f & 31;
        *reinterpret_cast<float4*>(&wlds[r * 132 + c4 * 4]) = pf[j];
      }
      // issue prefetch of chunk ph+2
      if (ph < 4) {
        const float* p = csrc[ph + 2]; const int st = cstr[ph + 2];
        #pragma unroll
        for (int j = 0; j < 8; ++j) {
          const int f = j * MT + tid, r = f >> 5, c4 = f & 31;
          pf[j] = *reinterpret_cast<const float4*>(p + r * st + c4 * 4);
        }
      }
    }
    if (half == 1) {
      // layer complete: write its outputs to act
      *reinterpret_cast<float4*>(&act[col][og * 4]) =
          make_float4(resA[0], resA[1], resA[2], resA[3]);
      *reinterpret_cast<float4*>(&act[col][64 + og * 4]) =
          make_float4(resB[0], resB[1], resB[2], resB[3]);
    }
    __syncthreads();
  }

  // epilogue: out[q] = W3 . h2[:,col] + b3 ; 16 lanes per column
  {
    const int ecol = tid >> 4, ek = tid & 15;
    const float4 x1 = *reinterpret_cast<const float4*>(&act[ecol][ek * 8]);
    const float4 w1v = *reinterpret_cast<const float4*>(W3 + ek * 8);
    const float4 x2 = *reinterpret_cast<const float4*>(&act[ecol][ek * 8 + 4]);
    const float4 w2v = *reinterpret_cast<const float4*>(W3 + ek * 8 + 4);
    float p = x1.x * w1v.x + x1.y * w1v.y + x1.z * w1v.z + x1.w * w1v.w
            + x2.x * w2v.x + x2.y * w2v.y + x2.z * w2v.z + x2.w * w2v.w;
    p += __shfl_xor(p, 1);
    p += __shfl_xor(p, 2);
    p += __shfl_xor(p, 4);
    p += __shfl_xor(p, 8);
    if (ek == 0) out[q0 + ecol] = p + b3[0];
  }
}

// ---------------------------------------------------------------------------
extern "C" void kernel_launch(void* const* d_in, const int* in_sizes, int n_in,
                              void* d_out, int out_size, void* d_ws, size_t ws_size,
                              hipStream_t stream) {
  const float* feats = (const float*)d_in[0];
  const int*   pidx  = (const int*)d_in[1];
  const int*   poff  = (const int*)d_in[2];
  const int*   boff  = (const int*)d_in[3];
  const float* lang  = (const float*)d_in[4];
  const float* Wf    = (const float*)d_in[5];
  const float* bf    = (const float*)d_in[6];
  const float* W1    = (const float*)d_in[7];
  const float* b1    = (const float*)d_in[8];
  const float* g1    = (const float*)d_in[9];
  const float* be1   = (const float*)d_in[10];
  const float* rm1   = (const float*)d_in[11];
  const float* rv1   = (const float*)d_in[12];
  const float* W2    = (const float*)d_in[13];
  const float* b2    = (const float*)d_in[14];
  const float* g2    = (const float*)d_in[15];
  const float* be2   = (const float*)d_in[16];
  const float* rm2   = (const float*)d_in[17];
  const float* rv2   = (const float*)d_in[18];
  const float* W3    = (const float*)d_in[19];
  const float* b3    = (const float*)d_in[20];
  float* out = (float*)d_out;

  int* srcmap = (int*)d_ws;
  int* bidp   = srcmap + N_;
  int* wrank  = bidp + N_;
  int* hist   = wrank + N_;
  float* lp = (float*)(hist + 32 * 32);
  float* s1 = lp + B_ * H_;
  float* t1 = s1 + H_;
  float* s2 = t1 + H_;
  float* t2 = s2 + H_;

  hipLaunchKernelGGL(k_map_a, dim3(32), dim3(256), 0, stream,
                     pidx, poff, boff, bidp, wrank, hist, srcmap, Wf, lang, lp);
  hipLaunchKernelGGL(k_map_b, dim3(1), dim3(1024), 0, stream,
                     bidp, wrank, hist, srcmap,
                     g1, be1, rm1, rv1, g2, be2, rm2, rv2, s1, t1, s2, t2);
  hipLaunchKernelGGL(k_mlp, dim3(MB), dim3(MT), 0, stream,
                     feats, Wf, bf, W1, b1, W2, b2, W3, b3,
                     srcmap, lp, s1, t1, s2, t2, out);
}

// Round 3
// 31.928 us; speedup vs baseline: 1.9400x; 1.9400x over previous
//
#include <hip/hip_runtime.h>
#include <math.h>

#define B_    32
#define PPB   256
#define N_    (B_*PPB)     // 8192 proposals / padded slots
#define M_    128
#define LANG_ 256
#define H_    128
#define EPS_  1e-5f
#define MC    32           // columns per MLP block
#define WA_OFF 120832      // byte offset of Wa in workspace (16B aligned)

typedef __attribute__((ext_vector_type(8))) short s16x8;
typedef __attribute__((ext_vector_type(4))) float f32x4;

static __device__ __forceinline__ unsigned short f2bf(float x) {
  unsigned int u = __float_as_uint(x);
  unsigned int r = (u + 0x7fff + ((u >> 16) & 1)) >> 16;
  return (unsigned short)r;
}
static __device__ __forceinline__ float bf2f(unsigned short h) {
  return __uint_as_float(((unsigned int)h) << 16);
}

// ---------------------------------------------------------------------------
// Kernel A: batch id + within-chunk stable rank + chunk histograms + fused
// lang projection + build frag-major hi/lo bf16 weight layout Wa.
// Wa group G = (L*8+s)*8+t ; lane l stores 8 bf16: o=t*16+(l&15),
// k elems {s'*32+4g..+3, s'*32+16+4g..+3}, g=l>>4, s'=s&3, hi if s<4.
// ---------------------------------------------------------------------------
__global__ __launch_bounds__(256) void k_map_a(
    const int* __restrict__ pidx, const int* __restrict__ poff,
    const int* __restrict__ boff, int* __restrict__ bid_g,
    int* __restrict__ wrank_g, int* __restrict__ hist_g,
    int* __restrict__ src_of_dest,
    const float* __restrict__ Wf, const float* __restrict__ lang,
    float* __restrict__ lp,
    const float* __restrict__ W1, const float* __restrict__ W2,
    unsigned short* __restrict__ wa)
{
  __shared__ int sb[33];
  __shared__ int sbid[256];
  __shared__ int shist[32];
  const int tid = threadIdx.x;
  const int i = blockIdx.x * 256 + tid;
  if (tid < 33) sb[tid] = boff[tid];
  if (tid < 32) shist[tid] = 0;
  __syncthreads();
  const int off = poff[i];
  const int fp  = pidx[2 * off + 1];
  int cnt = 0;
  #pragma unroll
  for (int j = 0; j < 33; ++j) cnt += (sb[j] <= fp) ? 1 : 0;
  int bd = cnt - 1;
  bd = bd < 0 ? 0 : (bd > 31 ? 31 : bd);
  sbid[tid] = bd;
  bid_g[i] = bd;
  src_of_dest[i] = -1;
  atomicAdd(&shist[bd], 1);
  __syncthreads();
  int r = 0;
  for (int j = 0; j < tid; ++j) r += (sbid[j] == bd) ? 1 : 0;
  wrank_g[i] = r;
  if (tid < 32) hist_g[blockIdx.x * 32 + tid] = shist[tid];

  // fused lang projection (batch = blockIdx.x)
  if (tid < 128) {
    const int o = tid;
    float acc = 0.f;
    for (int l = 0; l < LANG_; l += 4) {
      const float4 w = *reinterpret_cast<const float4*>(Wf + o * 384 + 128 + l);
      const float4 e = *reinterpret_cast<const float4*>(lang + blockIdx.x * LANG_ + l);
      acc += w.x * e.x + w.y * e.y + w.z * e.z + w.w * e.w;
    }
    lp[blockIdx.x * H_ + o] = acc;
  }

  // build Wa: 192 frag-groups over 128 waves
  const int lane = tid & 63, wid = tid >> 6;
  for (int G = blockIdx.x * 4 + wid; G < 192; G += 128) {
    const int L = G >> 6, s = (G >> 3) & 7, t = G & 7;
    const float* Wsrc; int str;
    if (L == 0)      { Wsrc = Wf; str = 384; }
    else if (L == 1) { Wsrc = W1; str = H_; }
    else             { Wsrc = W2; str = H_; }
    const int o = t * 16 + (lane & 15), g = lane >> 4, sp = s & 3;
    const bool hi = (s < 4);
    const float* rowp = Wsrc + (size_t)o * str + sp * 32 + g * 4;
    const float4 a = *reinterpret_cast<const float4*>(rowp);
    const float4 bq = *reinterpret_cast<const float4*>(rowp + 16);
    const float av[8] = {a.x, a.y, a.z, a.w, bq.x, bq.y, bq.z, bq.w};
    s16x8 v;
    #pragma unroll
    for (int e = 0; e < 8; ++e) {
      const unsigned short h = f2bf(av[e]);
      v[e] = (short)(hi ? h : f2bf(av[e] - bf2f(h)));
    }
    *reinterpret_cast<s16x8*>(wa + (size_t)G * 512 + lane * 8) = v;
  }
}

// ---------------------------------------------------------------------------
// Kernel B: cross-chunk scan per bin, scatter inverse map, fold BN.
// ---------------------------------------------------------------------------
__global__ __launch_bounds__(1024) void k_map_b(
    const int* __restrict__ bid_g, const int* __restrict__ wrank_g,
    const int* __restrict__ hist_g, int* __restrict__ src_of_dest,
    const float* __restrict__ g1, const float* __restrict__ be1,
    const float* __restrict__ rm1, const float* __restrict__ rv1,
    const float* __restrict__ g2, const float* __restrict__ be2,
    const float* __restrict__ rm2, const float* __restrict__ rv2,
    float* __restrict__ s1, float* __restrict__ t1,
    float* __restrict__ s2, float* __restrict__ t2)
{
  __shared__ int cb[32][32];
  const int tid = threadIdx.x;
  if (tid < 32) {
    int run = 0;
    for (int c = 0; c < 32; ++c) { cb[c][tid] = run; run += hist_g[c * 32 + tid]; }
  } else if (tid >= 512 && tid < 640) {
    const int o = tid - 512;
    const float s = g1[o] / sqrtf(rv1[o] + EPS_);
    s1[o] = s; t1[o] = be1[o] - rm1[o] * s;
  } else if (tid >= 640 && tid < 768) {
    const int o = tid - 640;
    const float s = g2[o] / sqrtf(rv2[o] + EPS_);
    s2[o] = s; t2[o] = be2[o] - rm2[o] * s;
  }
  __syncthreads();
  #pragma unroll
  for (int k = 0; k < 8; ++k) {
    const int i = tid * 8 + k;
    const int bd = bid_g[i];
    const int rank = cb[i >> 8][bd] + wrank_g[i];
    if (rank < PPB) src_of_dest[bd * PPB + rank] = i;
  }
}

// ---------------------------------------------------------------------------
// Kernel D: MFMA MLP. 256 blocks x 256 threads, 32 columns per block.
// hi/lo bf16 split, 2 K=256 passes per layer (exact (Whi+Wlo)(Xhi+Xlo)).
// A-frags: coalesced global loads into regs (reused both passes).
// X in LDS frag-major: every ds op bank-uniform b128.
// ---------------------------------------------------------------------------
__global__ __launch_bounds__(256) void k_mlp(
    const float* __restrict__ feats,
    const unsigned short* __restrict__ wa,
    const float* __restrict__ bf, const float* __restrict__ b1,
    const float* __restrict__ b2, const float* __restrict__ W3,
    const float* __restrict__ b3,
    const int* __restrict__ src_of_dest, const float* __restrict__ lpg,
    const float* __restrict__ s1, const float* __restrict__ t1,
    const float* __restrict__ s2, const float* __restrict__ t2,
    float* __restrict__ out)
{
  __shared__ s16x8 XbHi[512];      // [s4][g4][n32] 16B frags  (8 KB)
  __shared__ s16x8 XbLo[512];      //                           (8 KB)
  __shared__ float pbuf[1024];     // 8 x 128 params            (4 KB)
  __shared__ float outp[128];      // per-wave column partials

  const int tid = threadIdx.x;
  const int lane = tid & 63, wid = tid >> 6;
  const int q0 = blockIdx.x * MC;
  const int b = blockIdx.x >> 3;   // 8 blocks per batch

  // ---- params into LDS: [0]=bf+lp, [1]=b1,[2]=s1,[3]=t1,[4]=b2,[5]=s2,[6]=t2,[7]=W3
  #pragma unroll
  for (int j = tid; j < 1024; j += 256) {
    const int arr = j >> 7, o = j & 127;
    float v;
    switch (arr) {
      case 0: v = bf[o] + lpg[b * H_ + o]; break;
      case 1: v = b1[o]; break;
      case 2: v = s1[o]; break;
      case 3: v = t1[o]; break;
      case 4: v = b2[o]; break;
      case 5: v = s2[o]; break;
      case 6: v = t2[o]; break;
      default: v = W3[o]; break;
    }
    pbuf[j] = v;
  }

  // ---- stage gathered feats (hi/lo split) into Xb
  {
    const int n = tid & 31, u = tid >> 5;
    const int srow = src_of_dest[q0 + n];
    #pragma unroll
    for (int it = 0; it < 2; ++it) {
      const int sg = u + 8 * it, s = sg >> 2, g = sg & 3;
      const int k0 = s * 32 + g * 4;
      float4 a = make_float4(0.f, 0.f, 0.f, 0.f), bq = a;
      if (srow >= 0) {
        a  = *reinterpret_cast<const float4*>(feats + (size_t)srow * M_ + k0);
        bq = *reinterpret_cast<const float4*>(feats + (size_t)srow * M_ + k0 + 16);
      }
      const float av[8] = {a.x, a.y, a.z, a.w, bq.x, bq.y, bq.z, bq.w};
      s16x8 hv, lv;
      #pragma unroll
      for (int e = 0; e < 8; ++e) {
        const unsigned short h = f2bf(av[e]);
        hv[e] = (short)h;
        lv[e] = (short)f2bf(av[e] - bf2f(h));
      }
      XbHi[(s * 4 + g) * 32 + n] = hv;
      XbLo[(s * 4 + g) * 32 + n] = lv;
    }
  }
  __syncthreads();

  for (int L = 0; L < 3; ++L) {
    // A-frags from global (frag-major, coalesced), cached for both passes
    s16x8 A_[2][8];
    #pragma unroll
    for (int t = 0; t < 2; ++t)
      #pragma unroll
      for (int s = 0; s < 8; ++s)
        A_[t][s] = *reinterpret_cast<const s16x8*>(
            wa + (size_t)((L * 8 + s) * 8 + (wid * 2 + t)) * 512 + lane * 8);

    // B-frags from LDS into regs
    s16x8 Bh[4][2], Bl[4][2];
    #pragma unroll
    for (int s = 0; s < 4; ++s)
      #pragma unroll
      for (int nt = 0; nt < 2; ++nt) {
        const int idx = (s * 4 + (lane >> 4)) * 32 + nt * 16 + (lane & 15);
        Bh[s][nt] = XbHi[idx];
        Bl[s][nt] = XbLo[idx];
      }
    __syncthreads();   // all waves done reading Xb before anyone overwrites

    f32x4 acc[2][2];
    #pragma unroll
    for (int t = 0; t < 2; ++t)
      #pragma unroll
      for (int nt = 0; nt < 2; ++nt)
        acc[t][nt] = (f32x4){0.f, 0.f, 0.f, 0.f};

    // pass 1: [Whi|Wlo] . [Xhi;Xlo]
    #pragma unroll
    for (int sg = 0; sg < 8; ++sg)
      #pragma unroll
      for (int nt = 0; nt < 2; ++nt) {
        const s16x8 bb = (sg < 4) ? Bh[sg][nt] : Bl[sg - 4][nt];
        #pragma unroll
        for (int t = 0; t < 2; ++t)
          acc[t][nt] = __builtin_amdgcn_mfma_f32_16x16x32_bf16(
              A_[t][sg], bb, acc[t][nt], 0, 0, 0);
      }
    // pass 2: [Whi|Wlo] . [Xlo;Xhi]
    #pragma unroll
    for (int sg = 0; sg < 8; ++sg)
      #pragma unroll
      for (int nt = 0; nt < 2; ++nt) {
        const s16x8 bb = (sg < 4) ? Bl[sg][nt] : Bh[sg - 4][nt];
        #pragma unroll
        for (int t = 0; t < 2; ++t)
          acc[t][nt] = __builtin_amdgcn_mfma_f32_16x16x32_bf16(
              A_[t][sg], bb, acc[t][nt], 0, 0, 0);
      }

    if (L < 2) {
      // activation + split + write next-layer Xb (wave wid owns s=wid)
      #pragma unroll
      for (int nt = 0; nt < 2; ++nt) {
        s16x8 hv, lv;
        #pragma unroll
        for (int t = 0; t < 2; ++t)
          #pragma unroll
          for (int r = 0; r < 4; ++r) {
            const int o = (wid * 2 + t) * 16 + (lane >> 4) * 4 + r;
            const float z = acc[t][nt][r];
            float v;
            if (L == 0) v = fmaxf(z + pbuf[o], 0.f);
            else        v = fmaxf(z + pbuf[128 + o], 0.f) * pbuf[256 + o] + pbuf[384 + o];
            const unsigned short h = f2bf(v);
            hv[t * 4 + r] = (short)h;
            lv[t * 4 + r] = (short)f2bf(v - bf2f(h));
          }
        const int widx = (wid * 4 + (lane >> 4)) * 32 + nt * 16 + (lane & 15);
        XbHi[widx] = hv;
        XbLo[widx] = lv;
      }
      __syncthreads();
    } else {
      // final: BN2 then dot with W3, reduce over chan groups
      float p0 = 0.f, p1 = 0.f;
      #pragma unroll
      for (int t = 0; t < 2; ++t)
        #pragma unroll
        for (int r = 0; r < 4; ++r) {
          const int o = (wid * 2 + t) * 16 + (lane >> 4) * 4 + r;
          const float w3 = pbuf[896 + o];
          const float bb2 = pbuf[512 + o], ss2 = pbuf[640 + o], tt2 = pbuf[768 + o];
          p0 += w3 * (fmaxf(acc[t][0][r] + bb2, 0.f) * ss2 + tt2);
          p1 += w3 * (fmaxf(acc[t][1][r] + bb2, 0.f) * ss2 + tt2);
        }
      p0 += __shfl_xor(p0, 16); p0 += __shfl_xor(p0, 32);
      p1 += __shfl_xor(p1, 16); p1 += __shfl_xor(p1, 32);
      if (lane < 16) {
        outp[wid * 32 + lane] = p0;
        outp[wid * 32 + 16 + lane] = p1;
      }
      __syncthreads();
      if (tid < 32)
        out[q0 + tid] = outp[tid] + outp[32 + tid] + outp[64 + tid] + outp[96 + tid] + b3[0];
    }
  }
}

// ---------------------------------------------------------------------------
extern "C" void kernel_launch(void* const* d_in, const int* in_sizes, int n_in,
                              void* d_out, int out_size, void* d_ws, size_t ws_size,
                              hipStream_t stream) {
  const float* feats = (const float*)d_in[0];
  const int*   pidx  = (const int*)d_in[1];
  const int*   poff  = (const int*)d_in[2];
  const int*   boff  = (const int*)d_in[3];
  const float* lang  = (const float*)d_in[4];
  const float* Wf    = (const float*)d_in[5];
  const float* bf    = (const float*)d_in[6];
  const float* W1    = (const float*)d_in[7];
  const float* b1    = (const float*)d_in[8];
  const float* g1    = (const float*)d_in[9];
  const float* be1   = (const float*)d_in[10];
  const float* rm1   = (const float*)d_in[11];
  const float* rv1   = (const float*)d_in[12];
  const float* W2    = (const float*)d_in[13];
  const float* b2    = (const float*)d_in[14];
  const float* g2    = (const float*)d_in[15];
  const float* be2   = (const float*)d_in[16];
  const float* rm2   = (const float*)d_in[17];
  const float* rv2   = (const float*)d_in[18];
  const float* W3    = (const float*)d_in[19];
  const float* b3    = (const float*)d_in[20];
  float* out = (float*)d_out;

  int* srcmap = (int*)d_ws;                  // 32768 B
  int* bidp   = srcmap + N_;                 // 32768 B
  int* wrank  = bidp + N_;                   // 32768 B
  int* hist   = wrank + N_;                  // 4096 B
  float* lp = (float*)(hist + 32 * 32);      // 16384 B
  float* s1 = lp + B_ * H_;
  float* t1 = s1 + H_;
  float* s2 = t1 + H_;
  float* t2 = s2 + H_;
  unsigned short* wa = (unsigned short*)((char*)d_ws + WA_OFF);  // 196608 B

  hipLaunchKernelGGL(k_map_a, dim3(32), dim3(256), 0, stream,
                     pidx, poff, boff, bidp, wrank, hist, srcmap,
                     Wf, lang, lp, W1, W2, wa);
  hipLaunchKernelGGL(k_map_b, dim3(1), dim3(1024), 0, stream,
                     bidp, wrank, hist, srcmap,
                     g1, be1, rm1, rv1, g2, be2, rm2, rv2, s1, t1, s2, t2);
  hipLaunchKernelGGL(k_mlp, dim3(N_ / MC), dim3(256), 0, stream,
                     feats, wa, bf, b1, b2, W3, b3,
                     srcmap, lp, s1, t1, s2, t2, out);
}